// Round 6
// baseline (47.354 us; speedup 1.0000x reference)
//
#include <hip/hip_runtime.h>
#include <stdint.h>

#define BB 1024    // batches
#define TT 1024    // input bits per batch
#define NN 2048    // neurons
#define NBITS 16   // address bits
#define MM 65536   // table entries per neuron
#define BW 16      // u64 words per t (= BB/64)
#define NBKT 256   // sort buckets (256 entries = 1KB of table each)

// ---------- K1: transpose+pack input_bits (B x T int32) -> bitsT[t][w] ----------
__global__ void pack_transpose_kernel(const int* __restrict__ in,
                                      unsigned long long* __restrict__ bitsT) {
    const int lane = threadIdx.x & 63;
    const int wave = threadIdx.x >> 6;
    const int w  = blockIdx.y;
    const int t0 = blockIdx.x * 64 + wave * 16;
    const int b  = w * 64 + lane;
    const int* row = in + (size_t)b * TT;
    #pragma unroll
    for (int i = 0; i < 16; ++i) {
        const int t = t0 + i;
        const int v = row[t];
        unsigned long long m = __ballot(v != 0);
        if (lane == 0) bitsT[(size_t)t * BW + w] = m;
    }
}

// ---------- K3: one block per neuron; bucket-sorted gather (256 buckets) ----------
__global__ __launch_bounds__(256) void sorted_gather_kernel(
        const int* __restrict__ conn,
        const float* __restrict__ table,
        const unsigned long long* __restrict__ bitsT,
        unsigned long long* __restrict__ resbitsT) {
    __shared__ unsigned long long sb[NBITS * BW];   // 2 KB: bit words
    __shared__ unsigned int hist[NBKT];
    __shared__ unsigned int cursor[NBKT];
    __shared__ unsigned int sorted[BB];             // 4 KB: (addr<<16)|b
    __shared__ unsigned char resb[BB];              // 1 KB: result per b

    const int tid = threadIdx.x;
    const int n   = blockIdx.x;

    // stage the 16 needed bitsT rows. thread <-> (k=tid>>4, w=tid&15)
    {
        const int k = tid >> 4;
        const int w = tid & 15;
        const int t = conn[n * NBITS + k];          // broadcast among 16 threads
        sb[k * BW + w] = bitsT[(size_t)t * BW + w];
    }
    hist[tid] = 0;
    __syncthreads();

    // addresses for b = 4*tid + j, j=0..3 (all share word index tid>>4)
    const int wi = tid >> 4;
    unsigned long long wreg[NBITS];
    #pragma unroll
    for (int k = 0; k < NBITS; ++k) wreg[k] = sb[k * BW + wi];  // broadcast reads

    unsigned int addr[4];
    #pragma unroll
    for (int j = 0; j < 4; ++j) {
        const int bit = (4 * tid + j) & 63;
        unsigned int a = 0;
        #pragma unroll
        for (int k = 0; k < NBITS; ++k)
            a |= (unsigned int)((wreg[k] >> bit) & 1ull) << (NBITS - 1 - k);
        addr[j] = a;
        atomicAdd(&hist[a >> 8], 1u);
    }
    __syncthreads();

    // exclusive prefix sum over 256 buckets: wave 0, 4 counters per lane
    if (tid < 64) {
        const unsigned int h0 = hist[4 * tid + 0];
        const unsigned int h1 = hist[4 * tid + 1];
        const unsigned int h2 = hist[4 * tid + 2];
        const unsigned int h3 = hist[4 * tid + 3];
        const unsigned int tot = h0 + h1 + h2 + h3;
        unsigned int s = tot;
        #pragma unroll
        for (int d = 1; d < 64; d <<= 1) {
            const unsigned int t2 = (unsigned int)__shfl_up((int)s, d, 64);
            if (tid >= d) s += t2;
        }
        const unsigned int base = s - tot;          // exclusive across lanes
        cursor[4 * tid + 0] = base;
        cursor[4 * tid + 1] = base + h0;
        cursor[4 * tid + 2] = base + h0 + h1;
        cursor[4 * tid + 3] = base + h0 + h1 + h2;
    }
    __syncthreads();

    // scatter into sorted order (bucket granularity)
    #pragma unroll
    for (int j = 0; j < 4; ++j) {
        const unsigned int a   = addr[j];
        const unsigned int pos = atomicAdd(&cursor[a >> 8], 1u);
        sorted[pos] = (a << 16) | (unsigned int)(4 * tid + j);
    }
    __syncthreads();

    // gather in sorted order: wave wv covers sorted[wv*256 .. wv*256+255]
    const int lane = tid & 63;
    const int wv   = tid >> 6;
    const float* trow = table + (size_t)n * MM;
    unsigned int it[4];
    float v[4];
    #pragma unroll
    for (int j = 0; j < 4; ++j) it[j] = sorted[wv * 256 + j * 64 + lane];
    #pragma unroll
    for (int j = 0; j < 4; ++j) v[j] = trow[it[j] >> 16];   // 4 gathers in flight
    #pragma unroll
    for (int j = 0; j < 4; ++j)
        resb[it[j] & 0xFFFFu] = (v[j] == 1.0f) ? 1 : 0;
    __syncthreads();

    // pack: word w covers b in [w*64, w*64+64)
    #pragma unroll
    for (int w4 = 0; w4 < 4; ++w4) {
        const int w = wv * 4 + w4;
        const unsigned long long m = __ballot(resb[w * 64 + lane] != 0);
        if (lane == 0) resbitsT[(size_t)w * NN + n] = m;
    }
}

// ---------- K4: expand resbitsT bits -> out[b][n] int32, fully coalesced ----------
__global__ void expand_kernel(const unsigned long long* __restrict__ resbitsT,
                              int* __restrict__ out) {
    const int idx = blockIdx.x * 256 + threadIdx.x;   // idx = b*NN + n
    const int n = idx & (NN - 1);
    const int b = idx >> 11;
    const unsigned long long w = resbitsT[(size_t)(b >> 6) * NN + n]; // L2-resident
    const int r = (int)((w >> (b & 63)) & 1ull);
    __builtin_nontemporal_store(r, &out[idx]);
}

// ---------- fallback (direct lookup, needs only 128KB ws) ----------
__global__ __launch_bounds__(256) void lookup_direct_kernel(
        const int* __restrict__ conn,
        const float* __restrict__ table,
        const unsigned long long* __restrict__ bitsT,
        int* __restrict__ out) {
    const int tn = threadIdx.x & 15;
    const int s  = threadIdx.x >> 4;
    const int n  = blockIdx.x * 16 + tn;
    const int b0 = blockIdx.y * 256 + s * 16;
    int tk[NBITS];
    #pragma unroll
    for (int k = 0; k < NBITS; ++k) tk[k] = conn[n * NBITS + k];
    unsigned int hw[NBITS];
    const int w  = b0 >> 6;
    const int jb = b0 & 63;
    #pragma unroll
    for (int k = 0; k < NBITS; ++k) {
        unsigned long long word = bitsT[(size_t)tk[k] * BW + w];
        hw[k] = (unsigned int)(word >> jb) & 0xFFFFu;
    }
    const float* trow = table + (size_t)n * MM;
    #pragma unroll
    for (int j = 0; j < 16; ++j) {
        unsigned int a = 0;
        #pragma unroll
        for (int k = 0; k < NBITS; ++k)
            a |= ((hw[k] >> j) & 1u) << (NBITS - 1 - k);
        out[(size_t)(b0 + j) * NN + n] = (trow[a] == 1.0f) ? 1 : 0;
    }
}

extern "C" void kernel_launch(void* const* d_in, const int* in_sizes, int n_in,
                              void* d_out, int out_size, void* d_ws, size_t ws_size,
                              hipStream_t stream) {
    const int*   in_bits = (const int*)d_in[0];    // (B, T) int32
    const int*   conn    = (const int*)d_in[1];    // (N, NB) int32
    const float* table   = (const float*)d_in[2];  // (N, M) float32
    int* out = (int*)d_out;                        // (B, N) bool -> int32 0/1

    const size_t bitsT_bytes = (size_t)TT * BW * 8;          // 128 KB
    const size_t res_bytes   = (size_t)BW * NN * 8;          // 256 KB
    unsigned long long* bitsT    = (unsigned long long*)d_ws;
    unsigned long long* resbitsT = (unsigned long long*)((char*)d_ws + bitsT_bytes);

    dim3 g1(TT / 64, BB / 64);
    pack_transpose_kernel<<<g1, 256, 0, stream>>>(in_bits, bitsT);

    if (ws_size >= bitsT_bytes + res_bytes) {
        sorted_gather_kernel<<<NN, 256, 0, stream>>>(conn, table, bitsT, resbitsT);
        expand_kernel<<<(BB * NN) / 256, 256, 0, stream>>>(resbitsT, out);
    } else {
        dim3 g2(NN / 16, BB / 256);
        lookup_direct_kernel<<<g2, 256, 0, stream>>>(conn, table, bitsT, out);
    }
}

// Round 7
// 46.241 us; speedup vs baseline: 1.0241x; 1.0241x over previous
//
#include <hip/hip_runtime.h>
#include <stdint.h>

#define BB 1024    // batches
#define TT 1024    // input bits per batch
#define NN 2048    // neurons
#define NBITS 16   // address bits
#define MM 65536   // table entries per neuron
#define BW 16      // u64 words per t (= BB/64)

// ---------- K1: transpose+pack input_bits (B x T int32) -> bitsT[t][w] ----------
__global__ void pack_transpose_kernel(const int* __restrict__ in,
                                      unsigned long long* __restrict__ bitsT) {
    const int lane = threadIdx.x & 63;
    const int wave = threadIdx.x >> 6;
    const int w  = blockIdx.y;
    const int t0 = blockIdx.x * 64 + wave * 16;
    const int b  = w * 64 + lane;
    const int* row = in + (size_t)b * TT;
    #pragma unroll
    for (int i = 0; i < 16; ++i) {
        const int t = t0 + i;
        const int v = row[t];
        unsigned long long m = __ballot(v != 0);
        if (lane == 0) bitsT[(size_t)t * BW + w] = m;
    }
}

// ---------- K3: one block per neuron; bucket-sorted gather (64 buckets) ----------
// Per block: build all 1024 addresses for row n, counting-sort into 64
// buckets (1K entries = 4KB of table each) in LDS, gather in sorted order
// (each wave instr spans ~16KB of the row -> DRAM page locality, dup-line
// merge), pack results to bits: resbitsT[w][n] bit (b&63), w = b>>6.
__global__ __launch_bounds__(256) void sorted_gather_kernel(
        const int* __restrict__ conn,
        const float* __restrict__ table,
        const unsigned long long* __restrict__ bitsT,
        unsigned long long* __restrict__ resbitsT) {
    __shared__ unsigned long long sb[NBITS * BW];   // 2 KB: bit words
    __shared__ unsigned int hist[64];
    __shared__ unsigned int cursor[64];
    __shared__ unsigned int sorted[BB];             // 4 KB: (addr<<16)|b
    __shared__ unsigned char resb[BB];              // 1 KB: result per b

    const int tid = threadIdx.x;
    const int n   = blockIdx.x;

    // stage the 16 needed bitsT rows. thread <-> (k=tid>>4, w=tid&15)
    {
        const int k = tid >> 4;
        const int w = tid & 15;
        const int t = conn[n * NBITS + k];          // broadcast among 16 threads
        sb[k * BW + w] = bitsT[(size_t)t * BW + w]; // 128B coalesced per k-group
    }
    if (tid < 64) hist[tid] = 0;
    __syncthreads();

    // addresses for b = 4*tid + j, j=0..3 (all share word index tid>>4)
    const int wi = tid >> 4;
    unsigned long long wreg[NBITS];
    #pragma unroll
    for (int k = 0; k < NBITS; ++k) wreg[k] = sb[k * BW + wi];  // broadcast reads

    unsigned int addr[4];
    #pragma unroll
    for (int j = 0; j < 4; ++j) {
        const int bit = (4 * tid + j) & 63;
        unsigned int a = 0;
        #pragma unroll
        for (int k = 0; k < NBITS; ++k)
            a |= (unsigned int)((wreg[k] >> bit) & 1ull) << (NBITS - 1 - k);
        addr[j] = a;
        atomicAdd(&hist[a >> 10], 1u);
    }
    __syncthreads();

    // exclusive prefix sum over 64 buckets (wave 0)
    if (tid < 64) {
        const unsigned int v = hist[tid];
        unsigned int s = v;
        #pragma unroll
        for (int d = 1; d < 64; d <<= 1) {
            const unsigned int t2 = (unsigned int)__shfl_up((int)s, d, 64);
            if (tid >= d) s += t2;
        }
        cursor[tid] = s - v;                        // exclusive start
    }
    __syncthreads();

    // scatter into sorted order (bucket granularity)
    #pragma unroll
    for (int j = 0; j < 4; ++j) {
        const unsigned int a   = addr[j];
        const unsigned int pos = atomicAdd(&cursor[a >> 10], 1u);
        sorted[pos] = (a << 16) | (unsigned int)(4 * tid + j);
    }
    __syncthreads();

    // gather in sorted order: wave wv, iter j covers 64 consecutive sorted items
    const int lane = tid & 63;
    const int wv   = tid >> 6;
    const float* trow = table + (size_t)n * MM;
    unsigned int it[4];
    float v[4];
    #pragma unroll
    for (int j = 0; j < 4; ++j) it[j] = sorted[wv * 256 + j * 64 + lane];
    #pragma unroll
    for (int j = 0; j < 4; ++j) v[j] = trow[it[j] >> 16];   // 4 gathers in flight
    #pragma unroll
    for (int j = 0; j < 4; ++j)
        resb[it[j] & 0xFFFFu] = (v[j] == 1.0f) ? 1 : 0;
    __syncthreads();

    // pack: word w covers b in [w*64, w*64+64); bit lane = b = w*64+lane
    #pragma unroll
    for (int w4 = 0; w4 < 4; ++w4) {
        const int w = wv * 4 + w4;
        const unsigned long long m = __ballot(resb[w * 64 + lane] != 0);
        if (lane == 0) resbitsT[(size_t)w * NN + n] = m;
    }
}

// ---------- K4: expand resbitsT bits -> out[b][n] int32, fully coalesced ----------
__global__ void expand_kernel(const unsigned long long* __restrict__ resbitsT,
                              int* __restrict__ out) {
    const int idx = blockIdx.x * 256 + threadIdx.x;   // idx = b*NN + n
    const int n = idx & (NN - 1);
    const int b = idx >> 11;
    const unsigned long long w = resbitsT[(size_t)(b >> 6) * NN + n]; // L2-resident
    const int r = (int)((w >> (b & 63)) & 1ull);
    __builtin_nontemporal_store(r, &out[idx]);
}

// ---------- fallback (direct lookup, needs only 128KB ws) ----------
__global__ __launch_bounds__(256) void lookup_direct_kernel(
        const int* __restrict__ conn,
        const float* __restrict__ table,
        const unsigned long long* __restrict__ bitsT,
        int* __restrict__ out) {
    const int tn = threadIdx.x & 15;
    const int s  = threadIdx.x >> 4;
    const int n  = blockIdx.x * 16 + tn;
    const int b0 = blockIdx.y * 256 + s * 16;
    int tk[NBITS];
    #pragma unroll
    for (int k = 0; k < NBITS; ++k) tk[k] = conn[n * NBITS + k];
    unsigned int hw[NBITS];
    const int w  = b0 >> 6;
    const int jb = b0 & 63;
    #pragma unroll
    for (int k = 0; k < NBITS; ++k) {
        unsigned long long word = bitsT[(size_t)tk[k] * BW + w];
        hw[k] = (unsigned int)(word >> jb) & 0xFFFFu;
    }
    const float* trow = table + (size_t)n * MM;
    #pragma unroll
    for (int j = 0; j < 16; ++j) {
        unsigned int a = 0;
        #pragma unroll
        for (int k = 0; k < NBITS; ++k)
            a |= ((hw[k] >> j) & 1u) << (NBITS - 1 - k);
        out[(size_t)(b0 + j) * NN + n] = (trow[a] == 1.0f) ? 1 : 0;
    }
}

extern "C" void kernel_launch(void* const* d_in, const int* in_sizes, int n_in,
                              void* d_out, int out_size, void* d_ws, size_t ws_size,
                              hipStream_t stream) {
    const int*   in_bits = (const int*)d_in[0];    // (B, T) int32
    const int*   conn    = (const int*)d_in[1];    // (N, NB) int32
    const float* table   = (const float*)d_in[2];  // (N, M) float32
    int* out = (int*)d_out;                        // (B, N) bool -> int32 0/1

    const size_t bitsT_bytes = (size_t)TT * BW * 8;          // 128 KB
    const size_t res_bytes   = (size_t)BW * NN * 8;          // 256 KB
    unsigned long long* bitsT    = (unsigned long long*)d_ws;
    unsigned long long* resbitsT = (unsigned long long*)((char*)d_ws + bitsT_bytes);

    dim3 g1(TT / 64, BB / 64);
    pack_transpose_kernel<<<g1, 256, 0, stream>>>(in_bits, bitsT);

    if (ws_size >= bitsT_bytes + res_bytes) {
        sorted_gather_kernel<<<NN, 256, 0, stream>>>(conn, table, bitsT, resbitsT);
        expand_kernel<<<(BB * NN) / 256, 256, 0, stream>>>(resbitsT, out);
    } else {
        dim3 g2(NN / 16, BB / 256);
        lookup_direct_kernel<<<g2, 256, 0, stream>>>(conn, table, bitsT, out);
    }
}